// Round 4
// baseline (172.329 us; speedup 1.0000x reference)
//
#include <hip/hip_runtime.h>
#include <hip/hip_bf16.h>
#include <cstdint>
#include <math.h>

// Problem constants
#define SEQ    2048
#define DMODEL 1024
#define NHEAD  16
#define DHEAD  64
#define NZPAD  32   // per-row nonzero count padded to 32 (analytic max = 26)

typedef __bf16 bf16;
typedef __bf16 bf16x4 __attribute__((ext_vector_type(4)));
typedef __bf16 bf16x8 __attribute__((ext_vector_type(8)));
typedef float  f32x4  __attribute__((ext_vector_type(4)));

typedef __attribute__((address_space(3))) uint32_t lds_u32;
typedef __attribute__((address_space(1))) const uint32_t global_u32;

__device__ __forceinline__ void async_load16(const void* g, void* l) {
    __builtin_amdgcn_global_load_lds((global_u32*)g, (lds_u32*)l, 16, 0, 0);
}

// Analytic sparse-layout support for ORIGIN_SHAPE=(8,16,16), LOCAL_BLOCKS=3:
// support(s) = {t'*256 + (s&255), t'<t} u {(s&0x700) + h'*16 + (s&15), h'<h}
//            u {s-win..s}, win = min(s,3); disjoint; cnt = t+h+win+1 <= 26.
__device__ __forceinline__ int support_idx(int s, int c, int tt, int hh,
                                           int cnt) {
    const int jA = c * 256 + (s & 255);                    // axial-T, c < tt
    const int jB = (s & 0x700) + (c - tt) * 16 + (s & 15); // axial-H
    const int jC = s - (cnt - 1 - c);                      // causal window
    return c < tt ? jA : (c < tt + hh ? jB : (c < cnt ? jC : s));
}

// ---------------------------------------------------------------------------
// Prep is now ONLY the weight transpose-casts: W[K][N] fp32 -> WT[N][K] bf16.
// 64x64 tiles, float4 loads, bf16x4 (8B) stores. 1024 blocks (was 7680: the
// q/k/v cast is fused into proj3's A staging; the layout scan is analytic
// inside attn). Prep traffic 60MB -> 24MB.
__global__ __launch_bounds__(256) void prep_tr_kernel(
    const float* __restrict__ w0, const float* __restrict__ w1,
    const float* __restrict__ w2, const float* __restrict__ w3,
    bf16* __restrict__ t0, bf16* __restrict__ t1,
    bf16* __restrict__ t2, bf16* __restrict__ t3) {
    __shared__ float tile[64][65];
    const int z = blockIdx.x >> 8, rem = blockIdx.x & 255;
    const float* w = (z == 0) ? w0 : (z == 1) ? w1 : (z == 2) ? w2 : w3;
    bf16* t        = (z == 0) ? t0 : (z == 1) ? t1 : (z == 2) ? t2 : t3;
    const int kb = (rem >> 4) * 64, nb = (rem & 15) * 64;
    const int c4 = threadIdx.x & 15, rg = threadIdx.x >> 4;
#pragma unroll
    for (int i = 0; i < 4; ++i) {
        const int row = rg * 4 + i;
        const float4 v = *(const float4*)&w[(size_t)(kb + row) * DMODEL + nb + c4 * 4];
        tile[row][c4 * 4 + 0] = v.x; tile[row][c4 * 4 + 1] = v.y;
        tile[row][c4 * 4 + 2] = v.z; tile[row][c4 * 4 + 3] = v.w;
    }
    __syncthreads();
#pragma unroll
    for (int i = 0; i < 4; ++i) {
        const int n = rg * 4 + i;
        bf16x4 o;
        o[0] = (bf16)tile[c4 * 4 + 0][n]; o[1] = (bf16)tile[c4 * 4 + 1][n];
        o[2] = (bf16)tile[c4 * 4 + 2][n]; o[3] = (bf16)tile[c4 * 4 + 3][n];
        *(bf16x4*)&t[(size_t)(nb + n) * DMODEL + kb + c4 * 4] = o;
    }
}

// ---------------------------------------------------------------------------
// proj3: C_bf16 = cast_bf16(A_f32) @ BT^T + bias. A reg-staged from fp32
// (kills the qx round-trip): 4x float4 -> convert -> 2x ds_write_b128 into
// the XOR-swizzled chunk layout (store chunk ch at slot ch^(r&7); read of
// chunk q hits slot q^(r&7) -> retrieves q). Single barrier per K-step: all
// reads (buf=cur) and writes (buf=next) of one iteration complete before
// its barrier.
__global__ __launch_bounds__(256) void proj3_kernel(
    const float* __restrict__ qf, const float* __restrict__ kf, const float* __restrict__ vf,
    const bf16* __restrict__ wqT, const bf16* __restrict__ wkT, const bf16* __restrict__ wvT,
    const float* __restrict__ bq, const float* __restrict__ bk, const float* __restrict__ bv,
    bf16* __restrict__ qp, bf16* __restrict__ kp, bf16* __restrict__ vp) {
    constexpr int K = 1024, N = 1024, BK = 64, TM = 64, MI = 2;
    const int z = blockIdx.z;
    const float* A  = (z == 0) ? qf : (z == 1) ? kf : vf;
    const bf16* BT  = (z == 0) ? wqT : (z == 1) ? wkT : wvT;
    const float* bi = (z == 0) ? bq : (z == 1) ? bk : bv;
    bf16* C         = (z == 0) ? qp : (z == 1) ? kp : vp;

    __shared__ bf16 sA[2][TM * BK];
    __shared__ bf16 sB[2][128 * BK];
    const int tid = threadIdx.x;
    const int w = tid >> 6, lane = tid & 63;
    const int wm = w >> 1, wn = w & 1;
    const int lr = lane & 15, quad = lane >> 4;
    const int m0 = blockIdx.y * TM, n0 = blockIdx.x * 128;
    const int ar = tid >> 2, ak4 = tid & 3;   // A staging: row, k-quarter

    f32x4 acc[MI][4] = {};
    float bia[4];
#pragma unroll
    for (int ni = 0; ni < 4; ++ni) bia[ni] = bi[n0 + wn * 64 + ni * 16 + lr];

    float4 av[4];
    auto issueA = [&](int kt) {
        const float4* src = (const float4*)(A + (size_t)(m0 + ar) * K + kt + ak4 * 16);
#pragma unroll
        for (int i = 0; i < 4; ++i) av[i] = src[i];
    };
    auto writeA = [&](int buf) {
        bf16x8 c0, c1;
        c0[0] = (bf16)av[0].x; c0[1] = (bf16)av[0].y; c0[2] = (bf16)av[0].z; c0[3] = (bf16)av[0].w;
        c0[4] = (bf16)av[1].x; c0[5] = (bf16)av[1].y; c0[6] = (bf16)av[1].z; c0[7] = (bf16)av[1].w;
        c1[0] = (bf16)av[2].x; c1[1] = (bf16)av[2].y; c1[2] = (bf16)av[2].z; c1[3] = (bf16)av[2].w;
        c1[4] = (bf16)av[3].x; c1[5] = (bf16)av[3].y; c1[6] = (bf16)av[3].z; c1[7] = (bf16)av[3].w;
        const int s0 = (ak4 * 2) ^ (ar & 7), s1 = (ak4 * 2 + 1) ^ (ar & 7);
        *(bf16x8*)&sA[buf][ar * BK + s0 * 8] = c0;
        *(bf16x8*)&sA[buf][ar * BK + s1 * 8] = c1;
    };
    auto gloadB = [&](int buf, int kt) {
#pragma unroll
        for (int kk = 0; kk < 4; ++kk) {            // 128*8 = 1024 chunks
            const int cb = kk * 256 + w * 64;
            const int p = cb + lane;
            const int row = p >> 3, chl = p & 7;
            const int chg = chl ^ (row & 7);        // inverse-swizzled source
            async_load16(BT + (size_t)(n0 + row) * K + kt + chg * 8,
                         (char*)&sB[buf][0] + cb * 16);
        }
    };

    issueA(0);
    gloadB(0, 0);
    writeA(0);                                      // compiler waits av loads
    asm volatile("s_waitcnt vmcnt(0) lgkmcnt(0)" ::: "memory");
    __builtin_amdgcn_s_barrier();
    __builtin_amdgcn_sched_barrier(0);

    int cur = 0;
    for (int kt = 0; kt < K; kt += BK) {
        const bool more = (kt + BK) < K;
        if (more) { issueA(kt + BK); gloadB(cur ^ 1, kt + BK); }
#pragma unroll
        for (int ks = 0; ks < 2; ++ks) {
            bf16x8 af[MI], bfr[4];
#pragma unroll
            for (int mi = 0; mi < MI; ++mi) {
                const int row = wm * (TM / 2) + mi * 16 + lr;
                af[mi] = *(const bf16x8*)
                    &sA[cur][row * BK + ((ks * 4 + quad) ^ (row & 7)) * 8];
            }
#pragma unroll
            for (int ni = 0; ni < 4; ++ni) {
                const int row = wn * 64 + ni * 16 + lr;
                bfr[ni] = *(const bf16x8*)
                    &sB[cur][row * BK + ((ks * 4 + quad) ^ (row & 7)) * 8];
            }
            __builtin_amdgcn_s_setprio(1);
#pragma unroll
            for (int mi = 0; mi < MI; ++mi)
#pragma unroll
                for (int ni = 0; ni < 4; ++ni)
                    acc[mi][ni] = __builtin_amdgcn_mfma_f32_16x16x32_bf16(
                        af[mi], bfr[ni], acc[mi][ni], 0, 0, 0);
            __builtin_amdgcn_s_setprio(0);
        }
        if (more) writeA(cur ^ 1);                  // LDS writes to NEXT buf
        asm volatile("s_waitcnt vmcnt(0) lgkmcnt(0)" ::: "memory");
        __builtin_amdgcn_s_barrier();
        __builtin_amdgcn_sched_barrier(0);
        cur ^= 1;
    }

#pragma unroll
    for (int mi = 0; mi < MI; ++mi)
#pragma unroll
        for (int ni = 0; ni < 4; ++ni) {
            const int row = m0 + wm * (TM / 2) + mi * 16 + quad * 4;
            const int col = n0 + wn * 64 + ni * 16 + lr;
            const f32x4 vv = acc[mi][ni];
#pragma unroll
            for (int r = 0; r < 4; ++r)
                C[(size_t)(row + r) * N + col] = (bf16)(vv[r] + bia[ni]);
        }
}

// ---------------------------------------------------------------------------
// Final GEMM: C_f32 = A_bf16 @ BT^T + bias. TM=32 -> 512 WGs = 2 blocks/CU
// (was exactly 1/CU: every barrier stalled the whole CU).
__global__ __launch_bounds__(256) void gemm_final_kernel(
    const bf16* __restrict__ A, const bf16* __restrict__ BT,
    const float* __restrict__ bias, float* __restrict__ C) {
    constexpr int K = 1024, N = 1024, BK = 64, TM = 32, MI = 1;
    constexpr int ACH = TM * (BK / 8);        // 256 chunks
    constexpr int TCH = ACH + 128 * (BK / 8); // 1280 chunks -> 5 per thread
    __shared__ bf16 sA[2][TM * BK];
    __shared__ bf16 sB[2][128 * BK];
    const int tid = threadIdx.x;
    const int w = tid >> 6, lane = tid & 63;
    const int wm = w >> 1, wn = w & 1;
    const int lr = lane & 15, quad = lane >> 4;
    const int m0 = blockIdx.y * TM, n0 = blockIdx.x * 128;

    f32x4 acc[MI][4] = {};
    float bia[4];
#pragma unroll
    for (int ni = 0; ni < 4; ++ni) bia[ni] = bias[n0 + wn * 64 + ni * 16 + lr];

    auto stage = [&](int buf, int kt) {
#pragma unroll
        for (int kk = 0; kk < TCH / 256; ++kk) {
            const int cb = kk * 256 + w * 64;
            const int p = cb + lane;
            if (cb < ACH) {
                const int row = p >> 3, chl = p & 7;
                const int chg = chl ^ (row & 7);
                async_load16(A + (size_t)(m0 + row) * K + kt + chg * 8,
                             (char*)&sA[buf][0] + cb * 16);
            } else {
                const int p2 = p - ACH, row = p2 >> 3, chl = p2 & 7;
                const int chg = chl ^ (row & 7);
                async_load16(BT + (size_t)(n0 + row) * K + kt + chg * 8,
                             (char*)&sB[buf][0] + (cb - ACH) * 16);
            }
        }
    };

    stage(0, 0);
    asm volatile("s_waitcnt vmcnt(0)" ::: "memory");
    __builtin_amdgcn_s_barrier();
    __builtin_amdgcn_sched_barrier(0);

    int cur = 0;
    for (int kt = 0; kt < K; kt += BK) {
        if (kt + BK < K) stage(cur ^ 1, kt + BK);
#pragma unroll
        for (int ks = 0; ks < 2; ++ks) {
            bf16x8 af[MI], bfr[4];
#pragma unroll
            for (int mi = 0; mi < MI; ++mi) {
                const int row = wm * (TM / 2) + mi * 16 + lr;
                af[mi] = *(const bf16x8*)
                    &sA[cur][row * BK + ((ks * 4 + quad) ^ (row & 7)) * 8];
            }
#pragma unroll
            for (int ni = 0; ni < 4; ++ni) {
                const int row = wn * 64 + ni * 16 + lr;
                bfr[ni] = *(const bf16x8*)
                    &sB[cur][row * BK + ((ks * 4 + quad) ^ (row & 7)) * 8];
            }
            __builtin_amdgcn_s_setprio(1);
#pragma unroll
            for (int mi = 0; mi < MI; ++mi)
#pragma unroll
                for (int ni = 0; ni < 4; ++ni)
                    acc[mi][ni] = __builtin_amdgcn_mfma_f32_16x16x32_bf16(
                        af[mi], bfr[ni], acc[mi][ni], 0, 0, 0);
            __builtin_amdgcn_s_setprio(0);
        }
        asm volatile("s_waitcnt vmcnt(0)" ::: "memory");
        __builtin_amdgcn_s_barrier();
        __builtin_amdgcn_sched_barrier(0);
        cur ^= 1;
    }

#pragma unroll
    for (int mi = 0; mi < MI; ++mi)
#pragma unroll
        for (int ni = 0; ni < 4; ++ni) {
            const int row = m0 + wm * (TM / 2) + mi * 16 + quad * 4;
            const int col = n0 + wn * 64 + ni * 16 + lr;
            const f32x4 vv = acc[mi][ni];
#pragma unroll
            for (int r = 0; r < 4; ++r)
                C[(size_t)(row + r) * N + col] = vv[r] + bia[ni];
        }
}

// ---------------------------------------------------------------------------
// Sparse attention. Support set computed ANALYTICALLY in-register (no
// nzidx/nzcnt memory): scalar copies for PV (s wave-uniform -> SGPRs),
// vector copy for the per-lane K-gather index. XCD-chunked block swizzle
// keeps each XCD's gather working set (2 heads, 1.5MB) in its private L2.
__global__ __launch_bounds__(256) void attn_kernel(
    const bf16* __restrict__ qp, const bf16* __restrict__ kp, const bf16* __restrict__ vp,
    bf16* __restrict__ ao) {
    const int wv = threadIdx.x >> 6, lane = threadIdx.x & 63;
    constexpr int NB = NHEAD * SEQ / 4;           // 8192 blocks
    const int bid = (blockIdx.x & 7) * (NB >> 3) + (blockIdx.x >> 3);
    const int p = bid * 4 + wv;
    const int s = __builtin_amdgcn_readfirstlane(p & (SEQ - 1));
    const int h = __builtin_amdgcn_readfirstlane(p >> 11);
    const int hbase = h * DHEAD;
    const int hoff = hbase + lane;

    const int tt = (s >> 8) & 7, hh = (s >> 4) & 15;
    const int win = (s < 3) ? s : 3;
    const int cnt = tt + hh + win + 1;

    int t[NZPAD];                                  // s-uniform -> scalar regs
#pragma unroll
    for (int c = 0; c < NZPAD; ++c) t[c] = support_idx(s, c, tt, hh, cnt);

    // --- QK^T, lane=candidate
    const int c_lane = lane & 31;
    const int fo = (lane >> 5) << 5;               // feature offset: 0 or 32
    const int myT = support_idx(s, c_lane, tt, hh, cnt);  // per-lane (VALU)

    const bf16x8* qrow = (const bf16x8*)(qp + (size_t)s * DMODEL + hbase + fo);
    const bf16x8* krow = (const bf16x8*)(kp + (size_t)myT * DMODEL + hbase + fo);
    bf16x8 qc[4], kc[4];
#pragma unroll
    for (int j = 0; j < 4; ++j) { qc[j] = qrow[j]; kc[j] = krow[j]; }

    // hoist V loads (independent of softmax) to overlap latency; lane=feature
    float vvv[NZPAD];
#pragma unroll
    for (int c = 0; c < NZPAD; ++c)
        vvv[c] = (float)vp[(size_t)t[c] * DMODEL + hoff];

    float dot = 0.f;
#pragma unroll
    for (int j = 0; j < 4; ++j)
#pragma unroll
        for (int e = 0; e < 8; ++e)
            dot = fmaf((float)qc[j][e], (float)kc[j][e], dot);
    dot += __shfl_xor(dot, 32);   // combine feature halves -> full dot in lane c

    const float logit = (c_lane < cnt) ? dot * 0.125f : -1e30f;  // 1/sqrt(64)
    float m = logit;
    m = fmaxf(m, __shfl_xor(m, 1)); m = fmaxf(m, __shfl_xor(m, 2));
    m = fmaxf(m, __shfl_xor(m, 4)); m = fmaxf(m, __shfl_xor(m, 8));
    m = fmaxf(m, __shfl_xor(m, 16));
    const float e = __expf(logit - m);
    float ssum = e;
    ssum += __shfl_xor(ssum, 1); ssum += __shfl_xor(ssum, 2);
    ssum += __shfl_xor(ssum, 4); ssum += __shfl_xor(ssum, 8);
    ssum += __shfl_xor(ssum, 16);
    const float prob = e / ssum;

    float acc = 0.f;
#pragma unroll
    for (int c = 0; c < NZPAD; ++c) {
        const float pc = __uint_as_float(
            __builtin_amdgcn_readlane(__float_as_uint(prob), c));
        acc = fmaf(pc, vvv[c], acc);
    }
    ao[(size_t)s * DMODEL + hoff] = (bf16)acc;
}

// ---------------------------------------------------------------------------
extern "C" void kernel_launch(void* const* d_in, const int* in_sizes, int n_in,
                              void* d_out, int out_size, void* d_ws, size_t ws_size,
                              hipStream_t stream) {
    const float* query = (const float*)d_in[0];
    const float* key   = (const float*)d_in[1];
    const float* value = (const float*)d_in[2];
    const float* wq = (const float*)d_in[3];
    const float* bq = (const float*)d_in[4];
    const float* wk = (const float*)d_in[5];
    const float* bk = (const float*)d_in[6];
    const float* wv = (const float*)d_in[7];
    const float* bv = (const float*)d_in[8];
    const float* wo = (const float*)d_in[9];
    const float* bo = (const float*)d_in[10];
    float* out = (float*)d_out;

    char* ws = (char*)d_ws;
    auto alloc = [&](size_t bytes) {
        char* p = ws;
        ws += (bytes + 255) & ~(size_t)255;
        return p;
    };
    bf16* wqT = (bf16*)alloc((size_t)DMODEL * DMODEL * 2);
    bf16* wkT = (bf16*)alloc((size_t)DMODEL * DMODEL * 2);
    bf16* wvT = (bf16*)alloc((size_t)DMODEL * DMODEL * 2);
    bf16* woT = (bf16*)alloc((size_t)DMODEL * DMODEL * 2);
    bf16* qp  = (bf16*)alloc((size_t)SEQ * DMODEL * 2);
    bf16* kp  = (bf16*)alloc((size_t)SEQ * DMODEL * 2);
    bf16* vp  = (bf16*)alloc((size_t)SEQ * DMODEL * 2);
    bf16* ao  = (bf16*)alloc((size_t)SEQ * DMODEL * 2);

    // 1. weight transpose-casts only (q/k/v cast fused into proj3; layout analytic)
    prep_tr_kernel<<<dim3(1024), 256, 0, stream>>>(
        wq, wk, wv, wo, wqT, wkT, wvT, woT);
    // 2. q/k/v projections straight from fp32 (cast fused into A staging)
    proj3_kernel<<<dim3(8, 32, 3), 256, 0, stream>>>(
        query, key, value, wqT, wkT, wvT, bq, bk, bv, qp, kp, vp);
    // 3. sparse attention (analytic support, XCD-chunked swizzle)
    attn_kernel<<<dim3(NHEAD * SEQ / 4), 256, 0, stream>>>(qp, kp, vp, ao);
    // 4. output projection to fp32 (TM=32 -> 512 WGs, 2 blocks/CU)
    gemm_final_kernel<<<dim3(8, 64), 256, 0, stream>>>(ao, woT, bo, out);
}

// Round 5
// 158.149 us; speedup vs baseline: 1.0897x; 1.0897x over previous
//
#include <hip/hip_runtime.h>
#include <hip/hip_bf16.h>
#include <cstdint>
#include <math.h>

// Problem constants
#define SEQ    2048
#define DMODEL 1024
#define NHEAD  16
#define DHEAD  64
#define NZPAD  32   // per-row nonzero count padded to 32 (analytic max = 26)

typedef __bf16 bf16;
typedef __bf16 bf16x8 __attribute__((ext_vector_type(8)));
typedef float  f32x4  __attribute__((ext_vector_type(4)));

typedef __attribute__((address_space(3))) uint32_t lds_u32;
typedef __attribute__((address_space(1))) const uint32_t global_u32;

__device__ __forceinline__ void async_load16(const void* g, void* l) {
    __builtin_amdgcn_global_load_lds((global_u32*)g, (lds_u32*)l, 16, 0, 0);
}

// Analytic sparse-layout support for ORIGIN_SHAPE=(8,16,16), LOCAL_BLOCKS=3:
// support(s) = {t'*256 + (s&255), t'<t} u {(s&0x700) + h'*16 + (s&15), h'<h}
//            u {s-win..s}, win = min(s,3); disjoint; cnt = t+h+win+1 <= 26.
__device__ __forceinline__ int support_idx(int s, int c, int tt, int hh,
                                           int cnt) {
    const int jA = c * 256 + (s & 255);                    // axial-T, c < tt
    const int jB = (s & 0x700) + (c - tt) * 16 + (s & 15); // axial-H
    const int jC = s - (cnt - 1 - c);                      // causal window
    return c < tt ? jA : (c < tt + hh ? jB : (c < cnt ? jC : s));
}

// ---------------------------------------------------------------------------
// Merged preprocessing: fp32->bf16 casts of q/k/v (3072 blocks) + weight
// transpose-casts (4096 blocks). Layout support is analytic inside attn.
// NOTE round-4 lesson: keeping the bf16 qx/kx/vx round-trip is a WIN — the
// A-panels get re-read 24x by proj3 blocks, so halving their byte size beats
// saving one 12MB HBM write.
#define CAST_BLOCKS 3072
#define TR_BLOCKS   4096

__global__ __launch_bounds__(256) void prep_kernel(
    const float* __restrict__ q, const float* __restrict__ k, const float* __restrict__ v,
    bf16* __restrict__ qx, bf16* __restrict__ kx, bf16* __restrict__ vx,
    const float* __restrict__ w0, const float* __restrict__ w1,
    const float* __restrict__ w2, const float* __restrict__ w3,
    bf16* __restrict__ t0, bf16* __restrict__ t1,
    bf16* __restrict__ t2, bf16* __restrict__ t3) {
    __shared__ float tile[32][33];
    const int bid = blockIdx.x;
    if (bid < CAST_BLOCKS) {
        // ---- fp32 -> bf16 cast of q/k/v (8 elems per thread)
        const int z = bid >> 10;
        const float* src = (z == 0) ? q : (z == 1) ? k : v;
        bf16* dst        = (z == 0) ? qx : (z == 1) ? kx : vx;
        const int i = (bid & 1023) * 256 + threadIdx.x;
        const float4* s4 = (const float4*)src;
        float4 a = s4[i * 2 + 0];
        float4 b = s4[i * 2 + 1];
        bf16x8 o;
        o[0] = (bf16)a.x; o[1] = (bf16)a.y; o[2] = (bf16)a.z; o[3] = (bf16)a.w;
        o[4] = (bf16)b.x; o[5] = (bf16)b.y; o[6] = (bf16)b.z; o[7] = (bf16)b.w;
        ((bf16x8*)dst)[i] = o;
    } else {
        // ---- W[K][N] fp32 -> WT[N][K] bf16
        const int b = bid - CAST_BLOCKS;
        const int z = b >> 10, rem = b & 1023;
        const float* w = (z == 0) ? w0 : (z == 1) ? w1 : (z == 2) ? w2 : w3;
        bf16* t        = (z == 0) ? t0 : (z == 1) ? t1 : (z == 2) ? t2 : t3;
        const int tx = threadIdx.x & 31, ty = threadIdx.x >> 5;
        const int kbase = (rem >> 5) * 32, nbase = (rem & 31) * 32;
#pragma unroll
        for (int i = 0; i < 4; ++i)
            tile[ty + 8 * i][tx] = w[(size_t)(kbase + ty + 8 * i) * DMODEL + nbase + tx];
        __syncthreads();
#pragma unroll
        for (int i = 0; i < 4; ++i)
            t[(size_t)(nbase + ty + 8 * i) * DMODEL + kbase + tx] = (bf16)tile[tx][ty + 8 * i];
    }
}

// ---------------------------------------------------------------------------
// proj3: round-3 structure (best measured). TM=64, BK=64, 2-deep counted
// vmcnt(6) pipeline, XOR-swizzled LDS (rule #21: inverse-swizzled global
// source + same XOR on ds_read). NEW: 1-D grid with XCD-chunked decode —
// each XCD gets a contiguous run of 96 blocks (12 y-tiles x 8 x-tiles at
// fixed z): working set = 12 A-tiles (1.5MB bf16) + one BT panel (2MB)
// = 3.5MB, fits the private 4MB L2 (was: round-robin -> L3 thrash on the
// 24x-redundant A reads and 32x-redundant BT reads).
__global__ __launch_bounds__(256) void proj3_kernel(
    const bf16* __restrict__ qx, const bf16* __restrict__ kx, const bf16* __restrict__ vx,
    const bf16* __restrict__ wqT, const bf16* __restrict__ wkT, const bf16* __restrict__ wvT,
    const float* __restrict__ bq, const float* __restrict__ bk, const float* __restrict__ bv,
    bf16* __restrict__ qp, bf16* __restrict__ kp, bf16* __restrict__ vp) {
    constexpr int K = 1024, N = 1024, BK = 64, TM = 64, MI = 2;
    constexpr int ACH = TM * (BK / 8);        // 512 chunks
    constexpr int TCH = ACH + 128 * (BK / 8); // 1536 chunks -> 6 per thread

    // XCD-chunked decode (768 blocks, 96 per XCD, bijective: 768 % 8 == 0)
    const int orig = blockIdx.x;
    const int flat = (orig & 7) * 96 + (orig >> 3);
    const int z = flat >> 8;                  // 256 blocks per z
    const int rem = flat & 255;
    const int m0 = (rem >> 3) * TM, n0 = (rem & 7) * 128;

    const bf16* A   = (z == 0) ? qx : (z == 1) ? kx : vx;
    const bf16* BT  = (z == 0) ? wqT : (z == 1) ? wkT : wvT;
    const float* bi = (z == 0) ? bq : (z == 1) ? bk : bv;
    bf16* C         = (z == 0) ? qp : (z == 1) ? kp : vp;

    __shared__ bf16 sA[2][TM * BK];
    __shared__ bf16 sB[2][128 * BK];
    const int tid = threadIdx.x;
    const int w = tid >> 6, lane = tid & 63;
    const int wm = w >> 1, wn = w & 1;
    const int lr = lane & 15, quad = lane >> 4;

    f32x4 acc[MI][4] = {};
    float bia[4];
#pragma unroll
    for (int ni = 0; ni < 4; ++ni) bia[ni] = bi[n0 + wn * 64 + ni * 16 + lr];

    auto stage = [&](int buf, int kt) {
#pragma unroll
        for (int kk = 0; kk < TCH / 256; ++kk) {
            const int cb = kk * 256 + w * 64;     // wave-uniform chunk base
            const int p  = cb + lane;             // linear LDS slot
            if (cb < ACH) {
                const int row = p >> 3, chl = p & 7;
                const int chg = chl ^ (row & 7);  // inverse-swizzled source
                async_load16(A + (size_t)(m0 + row) * K + kt + chg * 8,
                             (char*)&sA[buf][0] + cb * 16);
            } else {
                const int p2 = p - ACH, row = p2 >> 3, chl = p2 & 7;
                const int chg = chl ^ (row & 7);
                async_load16(BT + (size_t)(n0 + row) * K + kt + chg * 8,
                             (char*)&sB[buf][0] + (cb - ACH) * 16);
            }
        }
    };

    stage(0, 0);
    stage(1, BK);
    int cur = 0;
    for (int kt = 0; kt < K; kt += BK) {
        if (kt + BK < K) {
            asm volatile("s_waitcnt vmcnt(6)" ::: "memory");  // cur tile landed
        } else {
            asm volatile("s_waitcnt vmcnt(0)" ::: "memory");  // epilogue drain
        }
        __builtin_amdgcn_s_barrier();
        __builtin_amdgcn_sched_barrier(0);
#pragma unroll
        for (int ks = 0; ks < 2; ++ks) {            // two 16x16x32 k-substeps
            bf16x8 af[MI], bfr[4];
#pragma unroll
            for (int mi = 0; mi < MI; ++mi) {
                const int row = wm * (TM / 2) + mi * 16 + lr;
                af[mi] = *(const bf16x8*)
                    &sA[cur][row * BK + ((ks * 4 + quad) ^ (row & 7)) * 8];
            }
#pragma unroll
            for (int ni = 0; ni < 4; ++ni) {
                const int row = wn * 64 + ni * 16 + lr;
                bfr[ni] = *(const bf16x8*)
                    &sB[cur][row * BK + ((ks * 4 + quad) ^ (row & 7)) * 8];
            }
            __builtin_amdgcn_s_setprio(1);
#pragma unroll
            for (int mi = 0; mi < MI; ++mi)
#pragma unroll
                for (int ni = 0; ni < 4; ++ni)
                    acc[mi][ni] = __builtin_amdgcn_mfma_f32_16x16x32_bf16(
                        af[mi], bfr[ni], acc[mi][ni], 0, 0, 0);
            __builtin_amdgcn_s_setprio(0);
        }
        __builtin_amdgcn_s_barrier();               // all waves done reading cur
        __builtin_amdgcn_sched_barrier(0);
        if (kt + 2 * BK < K) stage(cur, kt + 2 * BK);  // restage freed buffer
        cur ^= 1;
    }

#pragma unroll
    for (int mi = 0; mi < MI; ++mi)
#pragma unroll
        for (int ni = 0; ni < 4; ++ni) {
            const int row = m0 + wm * (TM / 2) + mi * 16 + quad * 4;
            const int col = n0 + wn * 64 + ni * 16 + lr;
            const f32x4 vv = acc[mi][ni];
#pragma unroll
            for (int r = 0; r < 4; ++r)
                C[(size_t)(row + r) * N + col] = (bf16)(vv[r] + bia[ni]);
        }
}

// ---------------------------------------------------------------------------
// Final GEMM: C_f32 = A_bf16 @ BT^T + bias. TM=32 (512 blocks = 2/CU) with
// 1x4 wave grid: wave-tile 32x32 -> 4 ds_read_b128 per substep (was 5 with
// 16x64) and half the B-frag traffic. Same 2-deep counted pipeline
// (5 loads/stage -> vmcnt(5)). XCD-chunked decode: 64 blocks per XCD =
// 8 y-tiles (A 8x64KB) + one BT panel (2MB) = 2.5MB, fits private L2.
__global__ __launch_bounds__(256) void gemm_final_kernel(
    const bf16* __restrict__ A, const bf16* __restrict__ BT,
    const float* __restrict__ bias, float* __restrict__ C) {
    constexpr int K = 1024, N = 1024, BK = 64, TM = 32, MI = 2;
    constexpr int ACH = TM * (BK / 8);        // 256 chunks
    constexpr int TCH = ACH + 128 * (BK / 8); // 1280 chunks -> 5 per thread

    const int orig = blockIdx.x;              // 512 blocks, 64 per XCD
    const int flat = (orig & 7) * 64 + (orig >> 3);
    const int m0 = (flat >> 3) * TM, n0 = (flat & 7) * 128;

    __shared__ bf16 sA[2][TM * BK];
    __shared__ bf16 sB[2][128 * BK];
    const int tid = threadIdx.x;
    const int w = tid >> 6, lane = tid & 63;  // wn = w (1x4 wave grid)
    const int lr = lane & 15, quad = lane >> 4;

    f32x4 acc[MI][2] = {};
    float bia[2];
#pragma unroll
    for (int ni = 0; ni < 2; ++ni) bia[ni] = bias[n0 + w * 32 + ni * 16 + lr];

    auto stage = [&](int buf, int kt) {
#pragma unroll
        for (int kk = 0; kk < TCH / 256; ++kk) {
            const int cb = kk * 256 + w * 64;
            const int p = cb + lane;
            if (cb < ACH) {
                const int row = p >> 3, chl = p & 7;
                const int chg = chl ^ (row & 7);
                async_load16(A + (size_t)(m0 + row) * K + kt + chg * 8,
                             (char*)&sA[buf][0] + cb * 16);
            } else {
                const int p2 = p - ACH, row = p2 >> 3, chl = p2 & 7;
                const int chg = chl ^ (row & 7);
                async_load16(BT + (size_t)(n0 + row) * K + kt + chg * 8,
                             (char*)&sB[buf][0] + (cb - ACH) * 16);
            }
        }
    };

    stage(0, 0);
    stage(1, BK);
    int cur = 0;
    for (int kt = 0; kt < K; kt += BK) {
        if (kt + BK < K) {
            asm volatile("s_waitcnt vmcnt(5)" ::: "memory");
        } else {
            asm volatile("s_waitcnt vmcnt(0)" ::: "memory");
        }
        __builtin_amdgcn_s_barrier();
        __builtin_amdgcn_sched_barrier(0);
#pragma unroll
        for (int ks = 0; ks < 2; ++ks) {
            bf16x8 af[MI], bfr[2];
#pragma unroll
            for (int mi = 0; mi < MI; ++mi) {
                const int row = mi * 16 + lr;
                af[mi] = *(const bf16x8*)
                    &sA[cur][row * BK + ((ks * 4 + quad) ^ (row & 7)) * 8];
            }
#pragma unroll
            for (int ni = 0; ni < 2; ++ni) {
                const int row = w * 32 + ni * 16 + lr;
                bfr[ni] = *(const bf16x8*)
                    &sB[cur][row * BK + ((ks * 4 + quad) ^ (row & 7)) * 8];
            }
            __builtin_amdgcn_s_setprio(1);
#pragma unroll
            for (int mi = 0; mi < MI; ++mi)
#pragma unroll
                for (int ni = 0; ni < 2; ++ni)
                    acc[mi][ni] = __builtin_amdgcn_mfma_f32_16x16x32_bf16(
                        af[mi], bfr[ni], acc[mi][ni], 0, 0, 0);
            __builtin_amdgcn_s_setprio(0);
        }
        __builtin_amdgcn_s_barrier();
        __builtin_amdgcn_sched_barrier(0);
        if (kt + 2 * BK < K) stage(cur, kt + 2 * BK);
        cur ^= 1;
    }

#pragma unroll
    for (int mi = 0; mi < MI; ++mi)
#pragma unroll
        for (int ni = 0; ni < 2; ++ni) {
            const int row = m0 + mi * 16 + quad * 4;
            const int col = n0 + w * 32 + ni * 16 + lr;
            const f32x4 vv = acc[mi][ni];
#pragma unroll
            for (int r = 0; r < 4; ++r)
                C[(size_t)(row + r) * N + col] = vv[r] + bia[ni];
        }
}

// ---------------------------------------------------------------------------
// Sparse attention: analytic support in-register (no nzidx memory),
// lane=candidate QK layout, XCD-chunked block swizzle (2 heads = 1.5MB per
// XCD fits private L2), setprio around the FMA clusters (T5, m191: helps
// independent-wave attn by preempting other waves' load-issue).
__global__ __launch_bounds__(256) void attn_kernel(
    const bf16* __restrict__ qp, const bf16* __restrict__ kp, const bf16* __restrict__ vp,
    bf16* __restrict__ ao) {
    const int wv = threadIdx.x >> 6, lane = threadIdx.x & 63;
    constexpr int NB = NHEAD * SEQ / 4;           // 8192 blocks
    const int bid = (blockIdx.x & 7) * (NB >> 3) + (blockIdx.x >> 3);
    const int p = bid * 4 + wv;
    const int s = __builtin_amdgcn_readfirstlane(p & (SEQ - 1));
    const int h = __builtin_amdgcn_readfirstlane(p >> 11);
    const int hbase = h * DHEAD;
    const int hoff = hbase + lane;

    const int tt = (s >> 8) & 7, hh = (s >> 4) & 15;
    const int win = (s < 3) ? s : 3;
    const int cnt = tt + hh + win + 1;

    int t[NZPAD];                                  // s-uniform -> scalar regs
#pragma unroll
    for (int c = 0; c < NZPAD; ++c) t[c] = support_idx(s, c, tt, hh, cnt);

    // --- QK^T, lane=candidate
    const int c_lane = lane & 31;
    const int fo = (lane >> 5) << 5;               // feature offset: 0 or 32
    const int myT = support_idx(s, c_lane, tt, hh, cnt);  // per-lane (VALU)

    const bf16x8* qrow = (const bf16x8*)(qp + (size_t)s * DMODEL + hbase + fo);
    const bf16x8* krow = (const bf16x8*)(kp + (size_t)myT * DMODEL + hbase + fo);
    bf16x8 qc[4], kc[4];
#pragma unroll
    for (int j = 0; j < 4; ++j) { qc[j] = qrow[j]; kc[j] = krow[j]; }

    // hoist V loads (independent of softmax) to overlap latency; lane=feature
    float vvv[NZPAD];
#pragma unroll
    for (int c = 0; c < NZPAD; ++c)
        vvv[c] = (float)vp[(size_t)t[c] * DMODEL + hoff];

    float dot = 0.f;
    __builtin_amdgcn_s_setprio(1);
#pragma unroll
    for (int j = 0; j < 4; ++j)
#pragma unroll
        for (int e = 0; e < 8; ++e)
            dot = fmaf((float)qc[j][e], (float)kc[j][e], dot);
    __builtin_amdgcn_s_setprio(0);
    dot += __shfl_xor(dot, 32);   // combine feature halves -> full dot in lane c

    const float logit = (c_lane < cnt) ? dot * 0.125f : -1e30f;  // 1/sqrt(64)
    float m = logit;
    m = fmaxf(m, __shfl_xor(m, 1)); m = fmaxf(m, __shfl_xor(m, 2));
    m = fmaxf(m, __shfl_xor(m, 4)); m = fmaxf(m, __shfl_xor(m, 8));
    m = fmaxf(m, __shfl_xor(m, 16));
    const float e = __expf(logit - m);
    float ssum = e;
    ssum += __shfl_xor(ssum, 1); ssum += __shfl_xor(ssum, 2);
    ssum += __shfl_xor(ssum, 4); ssum += __shfl_xor(ssum, 8);
    ssum += __shfl_xor(ssum, 16);
    const float prob = e / ssum;

    float acc = 0.f;
    __builtin_amdgcn_s_setprio(1);
#pragma unroll
    for (int c = 0; c < NZPAD; ++c) {
        const float pc = __uint_as_float(
            __builtin_amdgcn_readlane(__float_as_uint(prob), c));
        acc = fmaf(pc, vvv[c], acc);
    }
    __builtin_amdgcn_s_setprio(0);
    ao[(size_t)s * DMODEL + hoff] = (bf16)acc;
}

// ---------------------------------------------------------------------------
extern "C" void kernel_launch(void* const* d_in, const int* in_sizes, int n_in,
                              void* d_out, int out_size, void* d_ws, size_t ws_size,
                              hipStream_t stream) {
    const float* query = (const float*)d_in[0];
    const float* key   = (const float*)d_in[1];
    const float* value = (const float*)d_in[2];
    const float* wq = (const float*)d_in[3];
    const float* bq = (const float*)d_in[4];
    const float* wk = (const float*)d_in[5];
    const float* bk = (const float*)d_in[6];
    const float* wv = (const float*)d_in[7];
    const float* bv = (const float*)d_in[8];
    const float* wo = (const float*)d_in[9];
    const float* bo = (const float*)d_in[10];
    float* out = (float*)d_out;

    char* ws = (char*)d_ws;
    auto alloc = [&](size_t bytes) {
        char* p = ws;
        ws += (bytes + 255) & ~(size_t)255;
        return p;
    };
    bf16* qx  = (bf16*)alloc((size_t)SEQ * DMODEL * 2);
    bf16* kx  = (bf16*)alloc((size_t)SEQ * DMODEL * 2);
    bf16* vx  = (bf16*)alloc((size_t)SEQ * DMODEL * 2);
    bf16* wqT = (bf16*)alloc((size_t)DMODEL * DMODEL * 2);
    bf16* wkT = (bf16*)alloc((size_t)DMODEL * DMODEL * 2);
    bf16* wvT = (bf16*)alloc((size_t)DMODEL * DMODEL * 2);
    bf16* woT = (bf16*)alloc((size_t)DMODEL * DMODEL * 2);
    bf16* qp  = (bf16*)alloc((size_t)SEQ * DMODEL * 2);
    bf16* kp  = (bf16*)alloc((size_t)SEQ * DMODEL * 2);
    bf16* vp  = (bf16*)alloc((size_t)SEQ * DMODEL * 2);
    bf16* ao  = (bf16*)alloc((size_t)SEQ * DMODEL * 2);

    // 1. merged prep: q/k/v casts + weight transposes (layout is analytic)
    prep_kernel<<<dim3(CAST_BLOCKS + TR_BLOCKS), 256, 0, stream>>>(
        query, key, value, qx, kx, vx,
        wq, wk, wv, wo, wqT, wkT, wvT, woT);
    // 2. q/k/v projections (768 blocks, XCD-chunked 1-D grid)
    proj3_kernel<<<dim3(768), 256, 0, stream>>>(
        qx, kx, vx, wqT, wkT, wvT, bq, bk, bv, qp, kp, vp);
    // 3. sparse attention (analytic support, XCD-chunked swizzle)
    attn_kernel<<<dim3(NHEAD * SEQ / 4), 256, 0, stream>>>(qp, kp, vp, ao);
    // 4. output projection to fp32 (512 blocks, XCD-chunked 1-D grid)
    gemm_final_kernel<<<dim3(512), 256, 0, stream>>>(ao, woT, bo, out);
}